// Round 2
// baseline (543.378 us; speedup 1.0000x reference)
//
#include <hip/hip_runtime.h>

#define NPTS 8192
#define BN   16384          // B * N
#define D    32
#define R2   0.0009f        // float32(0.03**2)
#define SIMT 0.7f
#define BLOCK 256
#define NBLKX (BN / BLOCK)  // 64
#define JSPLIT 32
#define JLEN  (NPTS / JSPLIT)   // 256
#define AFIELDS 34          // nbc, cnt, acc[32] — SoA stride BN

// ---------------------------------------------------------------------------
// pre: pack (x,y,z, leaf? 0.5*(sq-R2) : 1e30), inv-norm of emb, per-batch leafcnt
// Filter identity: d2 < R2  <=>  dot(pi,pj) - 0.5*sq_i > 0.5*(sq_j - R2)
// ---------------------------------------------------------------------------
__global__ __launch_bounds__(BLOCK) void pre_kernel(
    const float* __restrict__ pts, const float* __restrict__ emb,
    const int* __restrict__ leaf, float4* __restrict__ pts4,
    float* __restrict__ invn, int* __restrict__ leafcnt) {
  const int p = blockIdx.x * BLOCK + threadIdx.x;
  const float x = pts[3 * p + 0];
  const float y = pts[3 * p + 1];
  const float z = pts[3 * p + 2];
  const float sq = x * x + y * y + z * z;
  const int lf = leaf[p] > 0;
  float4 o;
  o.x = x; o.y = y; o.z = z;
  o.w = lf ? 0.5f * (sq - R2) : 1e30f;   // non-leaf j can never pass
  pts4[p] = o;

  const float4* er = (const float4*)(emb + (size_t)p * D);
  float ss = 0.f;
#pragma unroll
  for (int i = 0; i < D / 4; ++i) {
    float4 v = er[i];
    ss += v.x * v.x + v.y * v.y + v.z * v.z + v.w * v.w;
  }
  invn[p] = 1.0f / fmaxf(sqrtf(ss), 1e-8f);

  if (lf) atomicAdd(&leafcnt[p >> 13], 1);   // N = 8192 = 2^13
}

// ---------------------------------------------------------------------------
// pair scan: lane owns point i; wave-uniform j sweep (scalar loads), software
// prefetch 1 group ahead. Rare-path results go straight to atomic accumulator.
// accb layout: accb[f*BN + p], f in {0:nbc, 1:cnt, 2..33:acc[d]}
// ---------------------------------------------------------------------------
__global__ __launch_bounds__(BLOCK, 8) void pair_kernel(
    const float4* __restrict__ pts4, const float* __restrict__ emb,
    const float* __restrict__ invn, float* __restrict__ accb) {
  const int p = blockIdx.x * BLOCK + threadIdx.x;
  const int b = blockIdx.x >> 5;   // 32 blocks of 256 per batch of 8192
  const float4* __restrict__ pjb = pts4 + (size_t)b * NPTS;
  const float*  __restrict__ ejb = emb  + (size_t)b * NPTS * D;
  const float*  __restrict__ inb = invn + (size_t)b * NPTS;

  const float4 pi = pts4[p];
  const float mhsq = -0.5f * (pi.x * pi.x + pi.y * pi.y + pi.z * pi.z);
  const float inv_i = invn[p];

  float eni[D];
  {
    const float4* er = (const float4*)(emb + (size_t)p * D);
#pragma unroll
    for (int k = 0; k < D / 4; ++k) {
      float4 v = er[k];
      eni[4 * k + 0] = v.x * inv_i;
      eni[4 * k + 1] = v.y * inv_i;
      eni[4 * k + 2] = v.z * inv_i;
      eni[4 * k + 3] = v.w * inv_i;
    }
  }

  auto process = [&](const float4 c, const int jj) {
    // 3 fma + 1 cmp per pair on the hot path
    const float t = fmaf(pi.z, c.z, fmaf(pi.y, c.y, fmaf(pi.x, c.x, mhsq)));
    if (t > c.w) {                         // ~0.09% of pairs
      atomicAdd(&accb[0 * BN + p], 1.0f);  // nbc
      const float4* __restrict__ ej4 = (const float4*)(ejb + (size_t)jj * D);
      float s0 = 0.f, s1 = 0.f, s2 = 0.f, s3 = 0.f;
#pragma unroll
      for (int k = 0; k < D / 4; ++k) {
        const float4 v = ej4[k];
        s0 = fmaf(eni[4 * k + 0], v.x, s0);
        s1 = fmaf(eni[4 * k + 1], v.y, s1);
        s2 = fmaf(eni[4 * k + 2], v.z, s2);
        s3 = fmaf(eni[4 * k + 3], v.w, s3);
      }
      const float s = ((s0 + s1) + (s2 + s3)) * inb[jj];
      if (s > SIMT) {                      // ~self-pairs only
        atomicAdd(&accb[1 * BN + p], 1.0f);
#pragma unroll
        for (int k = 0; k < D / 4; ++k) {
          const float4 v = ej4[k];
          atomicAdd(&accb[(2 + 4 * k + 0) * BN + p], v.x);
          atomicAdd(&accb[(2 + 4 * k + 1) * BN + p], v.y);
          atomicAdd(&accb[(2 + 4 * k + 2) * BN + p], v.z);
          atomicAdd(&accb[(2 + 4 * k + 3) * BN + p], v.w);
        }
      }
    }
  };

  const int j0 = blockIdx.y * JLEN;
  const int j1 = j0 + JLEN;
  float4 c0 = pjb[j0 + 0], c1 = pjb[j0 + 1];
  float4 c2 = pjb[j0 + 2], c3 = pjb[j0 + 3];
  for (int j = j0; j < j1; j += 4) {
    const int jn = (j + 4 < j1) ? (j + 4) : j0;   // wrap keeps loads in-bounds
    const float4 n0 = pjb[jn + 0], n1 = pjb[jn + 1];
    const float4 n2 = pjb[jn + 2], n3 = pjb[jn + 3];
    process(c0, j + 0);
    process(c1, j + 1);
    process(c2, j + 2);
    process(c3, j + 3);
    c0 = n0; c1 = n1; c2 = n2; c3 = n3;
  }
}

// ---------------------------------------------------------------------------
// reduce + MLP + select
// ---------------------------------------------------------------------------
__global__ __launch_bounds__(BLOCK) void reduce_kernel(
    const float* __restrict__ accb,
    const float* __restrict__ emb, const int* __restrict__ leaf,
    const float* __restrict__ W1, const float* __restrict__ b1,
    const float* __restrict__ W2, const float* __restrict__ b2,
    const int* __restrict__ leafcnt, float* __restrict__ out) {
  const int p = blockIdx.x * BLOCK + threadIdx.x;
  const int b = blockIdx.x >> 5;

  const float nbc = accb[0 * BN + p];
  const float cnt = accb[1 * BN + p];

  float e[D];
  {
    const float4* er = (const float4*)(emb + (size_t)p * D);
#pragma unroll
    for (int i = 0; i < D / 4; ++i) {
      float4 v = er[i];
      e[4 * i + 0] = v.x; e[4 * i + 1] = v.y;
      e[4 * i + 2] = v.z; e[4 * i + 3] = v.w;
    }
  }

  const float rinv = 1.0f / fmaxf(cnt, 1.0f);
  float mean[D];
#pragma unroll
  for (int d = 0; d < D; ++d) mean[d] = accb[(2 + d) * BN + p] * rinv;

  // h = relu([e, mean] @ W1 + b1);  W1 is (2D, D) row-major (in, out)
  float h[D];
#pragma unroll
  for (int k = 0; k < D; ++k) h[k] = b1[k];
  for (int d = 0; d < D; ++d) {
    const float c = e[d];
    const float* __restrict__ w = W1 + (size_t)d * D;
#pragma unroll
    for (int k = 0; k < D; ++k) h[k] = fmaf(c, w[k], h[k]);
  }
  for (int d = 0; d < D; ++d) {
    const float c = mean[d];
    const float* __restrict__ w = W1 + (size_t)(D + d) * D;
#pragma unroll
    for (int k = 0; k < D; ++k) h[k] = fmaf(c, w[k], h[k]);
  }
#pragma unroll
  for (int k = 0; k < D; ++k) h[k] = fmaxf(h[k], 0.f);

  float o[D];
#pragma unroll
  for (int m = 0; m < D; ++m) o[m] = b2[m];
  for (int k = 0; k < D; ++k) {
    const float c = h[k];
    const float* __restrict__ w = W2 + (size_t)k * D;
#pragma unroll
    for (int m = 0; m < D; ++m) o[m] = fmaf(c, w[m], o[m]);
  }

  const bool ok = leafcnt[b] >= 10;
  const bool cond = (leaf[p] > 0) && (nbc >= 2.0f) && (cnt >= 1.0f) && ok;

  float4* outr = (float4*)(out + (size_t)p * D);
#pragma unroll
  for (int i = 0; i < D / 4; ++i) {
    float4 v;
    if (cond) { v.x = o[4*i+0]; v.y = o[4*i+1]; v.z = o[4*i+2]; v.w = o[4*i+3]; }
    else      { v.x = e[4*i+0]; v.y = e[4*i+1]; v.z = e[4*i+2]; v.w = e[4*i+3]; }
    outr[i] = v;
  }
}

// ---------------------------------------------------------------------------
extern "C" void kernel_launch(void* const* d_in, const int* in_sizes, int n_in,
                              void* d_out, int out_size, void* d_ws, size_t ws_size,
                              hipStream_t stream) {
  (void)in_sizes; (void)n_in; (void)out_size; (void)ws_size;
  const float* pts  = (const float*)d_in[0];
  const float* emb  = (const float*)d_in[1];
  const int*   leaf = (const int*)d_in[2];
  const float* W1   = (const float*)d_in[3];
  const float* b1   = (const float*)d_in[4];
  const float* W2   = (const float*)d_in[5];
  const float* b2   = (const float*)d_in[6];
  float* out = (float*)d_out;

  char* ws = (char*)d_ws;
  const size_t acc_bytes = (size_t)AFIELDS * BN * 4;   // 2.23 MB
  float* accb    = (float*)ws;
  int*   leafcnt = (int*)(ws + acc_bytes);
  float4* pts4   = (float4*)(ws + acc_bytes + 16);
  float*  invn   = (float*)(ws + acc_bytes + 16 + (size_t)BN * 16);

  hipMemsetAsync(accb, 0, acc_bytes + 16, stream);
  pre_kernel<<<NBLKX, BLOCK, 0, stream>>>(pts, emb, leaf, pts4, invn, leafcnt);
  pair_kernel<<<dim3(NBLKX, JSPLIT), BLOCK, 0, stream>>>(pts4, emb, invn, accb);
  reduce_kernel<<<NBLKX, BLOCK, 0, stream>>>(accb, emb, leaf, W1, b1, W2, b2,
                                             leafcnt, out);
}

// Round 3
// 274.709 us; speedup vs baseline: 1.9780x; 1.9780x over previous
//
#include <hip/hip_runtime.h>

#define NPTS 8192
#define BN   16384          // B * N
#define D    32
#define R2   0.0009f        // float32(0.03**2)
#define SIMT 0.7f
#define BLOCK 256
#define NBLKX (BN / BLOCK)  // 64
#define AFIELDS 34          // nbc, cnt, acc[32] — SoA, field stride BN

// ---------------------------------------------------------------------------
// pre: pack (x,y,z, leaf? 0.5*(sq-R2) : 1e30), inv-norm of emb, per-batch leafcnt
// Filter identity: d2 < R2  <=>  dot(pi,pj) - 0.5*sq_i > 0.5*(sq_j - R2)
// ---------------------------------------------------------------------------
__global__ __launch_bounds__(BLOCK) void pre_kernel(
    const float* __restrict__ pts, const float* __restrict__ emb,
    const int* __restrict__ leaf, float4* __restrict__ pts4,
    float* __restrict__ invn, int* __restrict__ leafcnt) {
  const int p = blockIdx.x * BLOCK + threadIdx.x;
  const float x = pts[3 * p + 0];
  const float y = pts[3 * p + 1];
  const float z = pts[3 * p + 2];
  const float sq = x * x + y * y + z * z;
  const int lf = leaf[p] > 0;
  float4 o;
  o.x = x; o.y = y; o.z = z;
  o.w = lf ? 0.5f * (sq - R2) : 1e30f;   // non-leaf j can never pass
  pts4[p] = o;

  const float4* er = (const float4*)(emb + (size_t)p * D);
  float ss = 0.f;
#pragma unroll
  for (int i = 0; i < D / 4; ++i) {
    float4 v = er[i];
    ss += v.x * v.x + v.y * v.y + v.z * v.z + v.w * v.w;
  }
  invn[p] = 1.0f / fmaxf(sqrtf(ss), 1e-8f);

  if (lf) atomicAdd(&leafcnt[p >> 13], 1);   // N = 8192 = 2^13
}

// ---------------------------------------------------------------------------
// pair scan: lane owns point i; wave-uniform j sweep in 8-wide SGPR-resident
// batches, double-buffered. No atomics: SoA partials per j-chunk; acc fields
// written only when cnt != 0 (reduce gates on cnt, so poisoned acc is never read).
// ---------------------------------------------------------------------------
__global__ __launch_bounds__(BLOCK) void pair_kernel(
    const float4* __restrict__ pts4, const float* __restrict__ emb,
    const float* __restrict__ invn, float* __restrict__ part, int jlen) {
  const int p = blockIdx.x * BLOCK + threadIdx.x;
  const int b = blockIdx.x >> 5;   // 32 blocks of 256 per batch of 8192
  const float4* __restrict__ pjb = pts4 + (size_t)b * NPTS;
  const float*  __restrict__ ejb = emb  + (size_t)b * NPTS * D;
  const float*  __restrict__ inb = invn + (size_t)b * NPTS;

  const float4 pi = pts4[p];
  const float mhsq = -0.5f * (pi.x * pi.x + pi.y * pi.y + pi.z * pi.z);
  const float inv_i = invn[p];
  const float4* __restrict__ ei4 = (const float4*)(emb + (size_t)p * D);

  float acc[D];
#pragma unroll
  for (int d = 0; d < D; ++d) acc[d] = 0.f;
  float nbc = 0.f, cnt = 0.f;

  auto process = [&](const float4 c, const int jj) {
    // hot path: 3 fma + 1 cmp per pair
    const float t = fmaf(pi.z, c.z, fmaf(pi.y, c.y, fmaf(pi.x, c.x, mhsq)));
    if (t > c.w) {                         // ~0.09% of pairs
      nbc += 1.0f;
      const float4* __restrict__ ej4 = (const float4*)(ejb + (size_t)jj * D);
      float s0 = 0.f, s1 = 0.f, s2 = 0.f, s3 = 0.f;
#pragma unroll
      for (int k = 0; k < D / 4; ++k) {
        const float4 vj = ej4[k];   // uniform -> scalar loads
        const float4 vi = ei4[k];   // per-lane, L1/L2-hot
        s0 = fmaf(vi.x, vj.x, s0);
        s1 = fmaf(vi.y, vj.y, s1);
        s2 = fmaf(vi.z, vj.z, s2);
        s3 = fmaf(vi.w, vj.w, s3);
      }
      const float s = ((s0 + s1) + (s2 + s3)) * inv_i * inb[jj];
      if (s > SIMT) {
        cnt += 1.0f;
#pragma unroll
        for (int k = 0; k < D / 4; ++k) {
          const float4 vj = ej4[k];
          acc[4 * k + 0] += vj.x;
          acc[4 * k + 1] += vj.y;
          acc[4 * k + 2] += vj.z;
          acc[4 * k + 3] += vj.w;
        }
      }
    }
  };

  const int j0 = blockIdx.y * jlen;
  const int j1 = j0 + jlen;

  float4 cur[8], nxt[8];
#pragma unroll
  for (int u = 0; u < 8; ++u) cur[u] = pjb[j0 + u];
  for (int j = j0; j < j1; j += 8) {
    const int jn = (j + 8 < j1) ? (j + 8) : j0;   // wrap keeps loads in-bounds
#pragma unroll
    for (int u = 0; u < 8; ++u) nxt[u] = pjb[jn + u];
#pragma unroll
    for (int u = 0; u < 8; ++u) process(cur[u], j + u);
#pragma unroll
    for (int u = 0; u < 8; ++u) cur[u] = nxt[u];
  }

  float* __restrict__ q = part + (size_t)blockIdx.y * AFIELDS * BN + p;
  q[0 * BN] = nbc;
  q[1 * BN] = cnt;
  if (cnt != 0.f) {
#pragma unroll
    for (int d = 0; d < D; ++d) q[(2 + d) * BN] = acc[d];
  }
}

// ---------------------------------------------------------------------------
// reduce + MLP + select
// ---------------------------------------------------------------------------
__global__ __launch_bounds__(BLOCK) void reduce_kernel(
    const float* __restrict__ part, int jsplit,
    const float* __restrict__ emb, const int* __restrict__ leaf,
    const float* __restrict__ W1, const float* __restrict__ b1,
    const float* __restrict__ W2, const float* __restrict__ b2,
    const int* __restrict__ leafcnt, float* __restrict__ out) {
  const int p = blockIdx.x * BLOCK + threadIdx.x;
  const int b = blockIdx.x >> 5;

  float nbc = 0.f, cnt = 0.f;
  float acc[D];
#pragma unroll
  for (int d = 0; d < D; ++d) acc[d] = 0.f;
  for (int js = 0; js < jsplit; ++js) {
    const float* __restrict__ q = part + (size_t)js * AFIELDS * BN + p;
    nbc += q[0 * BN];
    const float c = q[1 * BN];
    cnt += c;
    if (c != 0.f) {          // acc fields valid only when cnt != 0
#pragma unroll
      for (int d = 0; d < D; ++d) acc[d] += q[(2 + d) * BN];
    }
  }

  float e[D];
  {
    const float4* er = (const float4*)(emb + (size_t)p * D);
#pragma unroll
    for (int i = 0; i < D / 4; ++i) {
      float4 v = er[i];
      e[4 * i + 0] = v.x; e[4 * i + 1] = v.y;
      e[4 * i + 2] = v.z; e[4 * i + 3] = v.w;
    }
  }

  const float rinv = 1.0f / fmaxf(cnt, 1.0f);
  float mean[D];
#pragma unroll
  for (int d = 0; d < D; ++d) mean[d] = acc[d] * rinv;

  // h = relu([e, mean] @ W1 + b1);  W1 is (2D, D) row-major (in, out)
  float h[D];
#pragma unroll
  for (int k = 0; k < D; ++k) h[k] = b1[k];
  for (int d = 0; d < D; ++d) {
    const float c = e[d];
    const float* __restrict__ w = W1 + (size_t)d * D;
#pragma unroll
    for (int k = 0; k < D; ++k) h[k] = fmaf(c, w[k], h[k]);
  }
  for (int d = 0; d < D; ++d) {
    const float c = mean[d];
    const float* __restrict__ w = W1 + (size_t)(D + d) * D;
#pragma unroll
    for (int k = 0; k < D; ++k) h[k] = fmaf(c, w[k], h[k]);
  }
#pragma unroll
  for (int k = 0; k < D; ++k) h[k] = fmaxf(h[k], 0.f);

  float o[D];
#pragma unroll
  for (int m = 0; m < D; ++m) o[m] = b2[m];
  for (int k = 0; k < D; ++k) {
    const float c = h[k];
    const float* __restrict__ w = W2 + (size_t)k * D;
#pragma unroll
    for (int m = 0; m < D; ++m) o[m] = fmaf(c, w[m], o[m]);
  }

  const bool ok = leafcnt[b] >= 10;
  const bool cond = (leaf[p] > 0) && (nbc >= 2.0f) && (cnt >= 1.0f) && ok;

  float4* outr = (float4*)(out + (size_t)p * D);
#pragma unroll
  for (int i = 0; i < D / 4; ++i) {
    float4 v;
    if (cond) { v.x = o[4*i+0]; v.y = o[4*i+1]; v.z = o[4*i+2]; v.w = o[4*i+3]; }
    else      { v.x = e[4*i+0]; v.y = e[4*i+1]; v.z = e[4*i+2]; v.w = e[4*i+3]; }
    outr[i] = v;
  }
}

// ---------------------------------------------------------------------------
extern "C" void kernel_launch(void* const* d_in, const int* in_sizes, int n_in,
                              void* d_out, int out_size, void* d_ws, size_t ws_size,
                              hipStream_t stream) {
  (void)in_sizes; (void)n_in; (void)out_size;
  const float* pts  = (const float*)d_in[0];
  const float* emb  = (const float*)d_in[1];
  const int*   leaf = (const int*)d_in[2];
  const float* W1   = (const float*)d_in[3];
  const float* b1   = (const float*)d_in[4];
  const float* W2   = (const float*)d_in[5];
  const float* b2   = (const float*)d_in[6];
  float* out = (float*)d_out;

  char* ws = (char*)d_ws;
  float4* pts4   = (float4*)ws;                                   // 256 KB
  float*  invn   = (float*)(ws + (size_t)BN * 16);                // 64 KB
  int*    leafcnt= (int*)(ws + (size_t)BN * 16 + (size_t)BN * 4); // 16 B
  float*  part   = (float*)(ws + (size_t)BN * 16 + (size_t)BN * 4 + 256);
  const size_t fixed = (size_t)BN * 16 + (size_t)BN * 4 + 256;

  int jsplit = 1;
  const size_t chunk = (size_t)AFIELDS * BN * 4;   // 2.23 MB per j-chunk
  if (fixed + 32 * chunk <= ws_size)      jsplit = 32;
  else if (fixed + 16 * chunk <= ws_size) jsplit = 16;
  else if (fixed + 8 * chunk <= ws_size)  jsplit = 8;
  else if (fixed + 4 * chunk <= ws_size)  jsplit = 4;
  else if (fixed + 2 * chunk <= ws_size)  jsplit = 2;

  hipMemsetAsync(leafcnt, 0, 2 * sizeof(int), stream);
  pre_kernel<<<NBLKX, BLOCK, 0, stream>>>(pts, emb, leaf, pts4, invn, leafcnt);
  pair_kernel<<<dim3(NBLKX, jsplit), BLOCK, 0, stream>>>(pts4, emb, invn, part,
                                                         NPTS / jsplit);
  reduce_kernel<<<NBLKX, BLOCK, 0, stream>>>(part, jsplit, emb, leaf, W1, b1,
                                             W2, b2, leafcnt, out);
}

// Round 4
// 184.235 us; speedup vs baseline: 2.9494x; 1.4911x over previous
//
#include <hip/hip_runtime.h>

#define NPTS 8192
#define BN   16384          // B * N
#define D    32
#define R2   0.0009f        // float32(0.03**2)
#define SIMT 0.7f
#define BLOCK 256
#define NBLKX (BN / BLOCK)  // 64
#define AFIELDS 34          // nbc, cnt, acc[32] — SoA, field stride BN

// ---------------------------------------------------------------------------
// pre: pack (x,y,z, leaf? 0.5*(sq-R2) : 1e30), inv-norm of emb, per-batch leafcnt
// Filter identity: d2 < R2  <=>  dot(pi,pj) - 0.5*sq_i > 0.5*(sq_j - R2)
// leafcnt via wave-ballot + one atomic per wave (R3's per-thread atomics to a
// single address serialized at ~10ns each -> 90us; this is 256 atomics total).
// ---------------------------------------------------------------------------
__global__ __launch_bounds__(BLOCK) void pre_kernel(
    const float* __restrict__ pts, const float* __restrict__ emb,
    const int* __restrict__ leaf, float4* __restrict__ pts4,
    float* __restrict__ invn, int* __restrict__ leafcnt) {
  const int p = blockIdx.x * BLOCK + threadIdx.x;
  const float x = pts[3 * p + 0];
  const float y = pts[3 * p + 1];
  const float z = pts[3 * p + 2];
  const float sq = x * x + y * y + z * z;
  const int lf = leaf[p] > 0;
  float4 o;
  o.x = x; o.y = y; o.z = z;
  o.w = lf ? 0.5f * (sq - R2) : 1e30f;   // non-leaf j can never pass
  pts4[p] = o;

  const float4* er = (const float4*)(emb + (size_t)p * D);
  float ss = 0.f;
#pragma unroll
  for (int i = 0; i < D / 4; ++i) {
    float4 v = er[i];
    ss += v.x * v.x + v.y * v.y + v.z * v.z + v.w * v.w;
  }
  invn[p] = 1.0f / fmaxf(sqrtf(ss), 1e-8f);

  const unsigned long long m = __ballot(lf);   // wave64 mask
  if ((threadIdx.x & 63) == 0)
    atomicAdd(&leafcnt[p >> 13], (int)__popcll(m));   // N = 8192 = 2^13
}

// ---------------------------------------------------------------------------
// pair scan: lane owns point i; wave-uniform j sweep in 8-wide SGPR-resident
// batches, double-buffered. No atomics: SoA partials per j-chunk; acc fields
// written only when cnt != 0 (reduce gates on cnt, so poisoned acc is never read).
// ---------------------------------------------------------------------------
__global__ __launch_bounds__(BLOCK) void pair_kernel(
    const float4* __restrict__ pts4, const float* __restrict__ emb,
    const float* __restrict__ invn, float* __restrict__ part, int jlen) {
  const int p = blockIdx.x * BLOCK + threadIdx.x;
  const int b = blockIdx.x >> 5;   // 32 blocks of 256 per batch of 8192
  const float4* __restrict__ pjb = pts4 + (size_t)b * NPTS;
  const float*  __restrict__ ejb = emb  + (size_t)b * NPTS * D;
  const float*  __restrict__ inb = invn + (size_t)b * NPTS;

  const float4 pi = pts4[p];
  const float mhsq = -0.5f * (pi.x * pi.x + pi.y * pi.y + pi.z * pi.z);
  const float inv_i = invn[p];
  const float4* __restrict__ ei4 = (const float4*)(emb + (size_t)p * D);

  float acc[D];
#pragma unroll
  for (int d = 0; d < D; ++d) acc[d] = 0.f;
  float nbc = 0.f, cnt = 0.f;

  auto process = [&](const float4 c, const int jj) {
    // hot path: 3 fma + 1 cmp per pair
    const float t = fmaf(pi.z, c.z, fmaf(pi.y, c.y, fmaf(pi.x, c.x, mhsq)));
    if (t > c.w) {                         // ~0.09% of pairs
      nbc += 1.0f;
      const float4* __restrict__ ej4 = (const float4*)(ejb + (size_t)jj * D);
      float s0 = 0.f, s1 = 0.f, s2 = 0.f, s3 = 0.f;
#pragma unroll
      for (int k = 0; k < D / 4; ++k) {
        const float4 vj = ej4[k];   // uniform -> scalar loads
        const float4 vi = ei4[k];   // per-lane, L1/L2-hot
        s0 = fmaf(vi.x, vj.x, s0);
        s1 = fmaf(vi.y, vj.y, s1);
        s2 = fmaf(vi.z, vj.z, s2);
        s3 = fmaf(vi.w, vj.w, s3);
      }
      const float s = ((s0 + s1) + (s2 + s3)) * inv_i * inb[jj];
      if (s > SIMT) {
        cnt += 1.0f;
#pragma unroll
        for (int k = 0; k < D / 4; ++k) {
          const float4 vj = ej4[k];
          acc[4 * k + 0] += vj.x;
          acc[4 * k + 1] += vj.y;
          acc[4 * k + 2] += vj.z;
          acc[4 * k + 3] += vj.w;
        }
      }
    }
  };

  const int j0 = blockIdx.y * jlen;
  const int j1 = j0 + jlen;

  float4 cur[8], nxt[8];
#pragma unroll
  for (int u = 0; u < 8; ++u) cur[u] = pjb[j0 + u];
  for (int j = j0; j < j1; j += 8) {
    const int jn = (j + 8 < j1) ? (j + 8) : j0;   // wrap keeps loads in-bounds
#pragma unroll
    for (int u = 0; u < 8; ++u) nxt[u] = pjb[jn + u];
#pragma unroll
    for (int u = 0; u < 8; ++u) process(cur[u], j + u);
#pragma unroll
    for (int u = 0; u < 8; ++u) cur[u] = nxt[u];
  }

  float* __restrict__ q = part + (size_t)blockIdx.y * AFIELDS * BN + p;
  q[0 * BN] = nbc;
  q[1 * BN] = cnt;
  if (cnt != 0.f) {
#pragma unroll
    for (int d = 0; d < D; ++d) q[(2 + d) * BN] = acc[d];
  }
}

// ---------------------------------------------------------------------------
// reduce + MLP + select
// ---------------------------------------------------------------------------
__global__ __launch_bounds__(BLOCK) void reduce_kernel(
    const float* __restrict__ part, int jsplit,
    const float* __restrict__ emb, const int* __restrict__ leaf,
    const float* __restrict__ W1, const float* __restrict__ b1,
    const float* __restrict__ W2, const float* __restrict__ b2,
    const int* __restrict__ leafcnt, float* __restrict__ out) {
  const int p = blockIdx.x * BLOCK + threadIdx.x;
  const int b = blockIdx.x >> 5;

  float nbc = 0.f, cnt = 0.f;
  float acc[D];
#pragma unroll
  for (int d = 0; d < D; ++d) acc[d] = 0.f;
  for (int js = 0; js < jsplit; ++js) {
    const float* __restrict__ q = part + (size_t)js * AFIELDS * BN + p;
    nbc += q[0 * BN];
    const float c = q[1 * BN];
    cnt += c;
    if (c != 0.f) {          // acc fields valid only when cnt != 0
#pragma unroll
      for (int d = 0; d < D; ++d) acc[d] += q[(2 + d) * BN];
    }
  }

  float e[D];
  {
    const float4* er = (const float4*)(emb + (size_t)p * D);
#pragma unroll
    for (int i = 0; i < D / 4; ++i) {
      float4 v = er[i];
      e[4 * i + 0] = v.x; e[4 * i + 1] = v.y;
      e[4 * i + 2] = v.z; e[4 * i + 3] = v.w;
    }
  }

  const float rinv = 1.0f / fmaxf(cnt, 1.0f);
  float mean[D];
#pragma unroll
  for (int d = 0; d < D; ++d) mean[d] = acc[d] * rinv;

  // h = relu([e, mean] @ W1 + b1);  W1 is (2D, D) row-major (in, out)
  float h[D];
#pragma unroll
  for (int k = 0; k < D; ++k) h[k] = b1[k];
  for (int d = 0; d < D; ++d) {
    const float c = e[d];
    const float* __restrict__ w = W1 + (size_t)d * D;
#pragma unroll
    for (int k = 0; k < D; ++k) h[k] = fmaf(c, w[k], h[k]);
  }
  for (int d = 0; d < D; ++d) {
    const float c = mean[d];
    const float* __restrict__ w = W1 + (size_t)(D + d) * D;
#pragma unroll
    for (int k = 0; k < D; ++k) h[k] = fmaf(c, w[k], h[k]);
  }
#pragma unroll
  for (int k = 0; k < D; ++k) h[k] = fmaxf(h[k], 0.f);

  float o[D];
#pragma unroll
  for (int m = 0; m < D; ++m) o[m] = b2[m];
  for (int k = 0; k < D; ++k) {
    const float c = h[k];
    const float* __restrict__ w = W2 + (size_t)k * D;
#pragma unroll
    for (int m = 0; m < D; ++m) o[m] = fmaf(c, w[m], o[m]);
  }

  const bool ok = leafcnt[b] >= 10;
  const bool cond = (leaf[p] > 0) && (nbc >= 2.0f) && (cnt >= 1.0f) && ok;

  float4* outr = (float4*)(out + (size_t)p * D);
#pragma unroll
  for (int i = 0; i < D / 4; ++i) {
    float4 v;
    if (cond) { v.x = o[4*i+0]; v.y = o[4*i+1]; v.z = o[4*i+2]; v.w = o[4*i+3]; }
    else      { v.x = e[4*i+0]; v.y = e[4*i+1]; v.z = e[4*i+2]; v.w = e[4*i+3]; }
    outr[i] = v;
  }
}

// ---------------------------------------------------------------------------
extern "C" void kernel_launch(void* const* d_in, const int* in_sizes, int n_in,
                              void* d_out, int out_size, void* d_ws, size_t ws_size,
                              hipStream_t stream) {
  (void)in_sizes; (void)n_in; (void)out_size;
  const float* pts  = (const float*)d_in[0];
  const float* emb  = (const float*)d_in[1];
  const int*   leaf = (const int*)d_in[2];
  const float* W1   = (const float*)d_in[3];
  const float* b1   = (const float*)d_in[4];
  const float* W2   = (const float*)d_in[5];
  const float* b2   = (const float*)d_in[6];
  float* out = (float*)d_out;

  char* ws = (char*)d_ws;
  float4* pts4   = (float4*)ws;                                   // 256 KB
  float*  invn   = (float*)(ws + (size_t)BN * 16);                // 64 KB
  int*    leafcnt= (int*)(ws + (size_t)BN * 16 + (size_t)BN * 4); // 16 B
  float*  part   = (float*)(ws + (size_t)BN * 16 + (size_t)BN * 4 + 256);
  const size_t fixed = (size_t)BN * 16 + (size_t)BN * 4 + 256;

  int jsplit = 1;
  const size_t chunk = (size_t)AFIELDS * BN * 4;   // 2.23 MB per j-chunk
  if (fixed + 32 * chunk <= ws_size)      jsplit = 32;
  else if (fixed + 16 * chunk <= ws_size) jsplit = 16;
  else if (fixed + 8 * chunk <= ws_size)  jsplit = 8;
  else if (fixed + 4 * chunk <= ws_size)  jsplit = 4;
  else if (fixed + 2 * chunk <= ws_size)  jsplit = 2;

  hipMemsetAsync(leafcnt, 0, 2 * sizeof(int), stream);
  pre_kernel<<<NBLKX, BLOCK, 0, stream>>>(pts, emb, leaf, pts4, invn, leafcnt);
  pair_kernel<<<dim3(NBLKX, jsplit), BLOCK, 0, stream>>>(pts4, emb, invn, part,
                                                         NPTS / jsplit);
  reduce_kernel<<<NBLKX, BLOCK, 0, stream>>>(part, jsplit, emb, leaf, W1, b1,
                                             W2, b2, leafcnt, out);
}

// Round 5
// 167.643 us; speedup vs baseline: 3.2413x; 1.0990x over previous
//
#include <hip/hip_runtime.h>

#define NPTS 8192
#define BN   16384          // B * N
#define D    32
#define R2   0.0009f        // float32(0.03**2)
#define SIMT 0.7f
#define RAD  0.03f
#define BLOCK 256
#define ZBINS 512
#define ZSCALE 1280.0f      // ZBINS / 0.4 (points lie in [0, 0.4))
#define AFIELDS 34          // nbc, cnt, acc[32] — SoA, field stride BN

// ---------------------------------------------------------------------------
// hist: z-histogram (all points + leaf-only), inv-norms, per-batch leaf count
// ---------------------------------------------------------------------------
__global__ __launch_bounds__(BLOCK) void hist_kernel(
    const float* __restrict__ pts, const float* __restrict__ emb,
    const int* __restrict__ leaf, float* __restrict__ invn,
    int* __restrict__ histA, int* __restrict__ histL, int* __restrict__ leafcnt) {
  const int p = blockIdx.x * BLOCK + threadIdx.x;
  const float z = pts[3 * p + 2];
  int bin = (int)(z * ZSCALE); if (bin > ZBINS - 1) bin = ZBINS - 1;
  const int b = p >> 13;
  const int lf = leaf[p] > 0;
  atomicAdd(&histA[b * ZBINS + bin], 1);
  if (lf) atomicAdd(&histL[b * ZBINS + bin], 1);

  const float4* er = (const float4*)(emb + (size_t)p * D);
  float ss = 0.f;
#pragma unroll
  for (int i = 0; i < D / 4; ++i) {
    float4 v = er[i];
    ss += v.x * v.x + v.y * v.y + v.z * v.z + v.w * v.w;
  }
  invn[p] = 1.0f / fmaxf(sqrtf(ss), 1e-8f);

  const unsigned long long m = __ballot(lf);
  if ((threadIdx.x & 63) == 0) atomicAdd(&leafcnt[b], (int)__popcll(m));
}

// ---------------------------------------------------------------------------
// scan: exclusive prefix sums for both hists, both batches; init cursors
// ---------------------------------------------------------------------------
__global__ __launch_bounds__(ZBINS) void scan_kernel(
    const int* __restrict__ histA, const int* __restrict__ histL,
    int* __restrict__ rsA, int* __restrict__ rsL,
    int* __restrict__ curA, int* __restrict__ curL) {
  __shared__ int buf[ZBINS];
  const int t = threadIdx.x;
  for (int sel = 0; sel < 4; ++sel) {
    const int b = sel & 1;
    const int* __restrict__ h = (sel < 2) ? histA : histL;
    int* __restrict__ rs = (sel < 2) ? rsA : rsL;
    int* __restrict__ cu = (sel < 2) ? curA : curL;
    const int mine = h[b * ZBINS + t];
    int val = mine;
    buf[t] = mine;
    __syncthreads();
    for (int off = 1; off < ZBINS; off <<= 1) {
      const int other = (t >= off) ? buf[t - off] : 0;
      __syncthreads();
      val += other;
      buf[t] = val;
      __syncthreads();
    }
    const int excl = val - mine;
    rs[b * (ZBINS + 1) + t] = excl;
    cu[b * ZBINS + t] = excl;
    if (t == ZBINS - 1) rs[b * (ZBINS + 1) + ZBINS] = val;
    __syncthreads();
  }
}

// ---------------------------------------------------------------------------
// scatter: counting-sort by z-bin. All points -> sortedA (+perm); leaf points
// -> compacted j-side arrays (pts4L with folded 0.5*(sq-R2), invL, embL).
// ---------------------------------------------------------------------------
__global__ __launch_bounds__(BLOCK) void scatter_kernel(
    const float* __restrict__ pts, const float* __restrict__ emb,
    const int* __restrict__ leaf, const float* __restrict__ invn,
    int* __restrict__ curA, int* __restrict__ curL,
    float4* __restrict__ sortedA, int* __restrict__ permA,
    float4* __restrict__ pts4L, float* __restrict__ invL,
    float* __restrict__ embL) {
  const int p = blockIdx.x * BLOCK + threadIdx.x;
  const float x = pts[3 * p + 0];
  const float y = pts[3 * p + 1];
  const float z = pts[3 * p + 2];
  const float sq = x * x + y * y + z * z;
  const int lf = leaf[p] > 0;
  const float inv = invn[p];
  int bin = (int)(z * ZSCALE); if (bin > ZBINS - 1) bin = ZBINS - 1;
  const int b = p >> 13;

  const int dst = b * NPTS + atomicAdd(&curA[b * ZBINS + bin], 1);
  sortedA[dst] = make_float4(x, y, z, lf ? inv : -inv);  // leaf in sign bit
  permA[dst] = p;

  if (lf) {
    const int dl = b * NPTS + atomicAdd(&curL[b * ZBINS + bin], 1);
    pts4L[dl] = make_float4(x, y, z, 0.5f * (sq - R2));
    invL[dl] = inv;
    const float4* __restrict__ s4 = (const float4*)(emb + (size_t)p * D);
    float4* __restrict__ d4 = (float4*)(embL + (size_t)dl * D);
#pragma unroll
    for (int k = 0; k < D / 4; ++k) d4[k] = s4[k];
  }
}

// ---------------------------------------------------------------------------
// pair: 1 wave per block; lanes own 64 z-consecutive sorted i's; wave-uniform
// sweep over the leaf-only j-window (|dz|<=0.03 guaranteed outside => prunable).
// grid.y splits the window YS ways. Partials at sorted index (coalesced).
// ---------------------------------------------------------------------------
template <int YS>
__global__ __launch_bounds__(64) void pair_kernel(
    const float4* __restrict__ sortedA, const int* __restrict__ permA,
    const float4* __restrict__ pts4L, const float* __restrict__ invL,
    const float* __restrict__ embL, const float* __restrict__ emb,
    const int* __restrict__ rsL, float* __restrict__ part) {
  const int sg = blockIdx.x * 64 + threadIdx.x;
  const int b = blockIdx.x >> 7;          // 128 blocks of 64 per batch
  const float4 A = sortedA[sg];
  const float inv_i = fabsf(A.w);
  const float mhsq = -0.5f * (A.x * A.x + A.y * A.y + A.z * A.z);
  const int p = permA[sg];
  const float4* __restrict__ ei4 = (const float4*)(emb + (size_t)p * D);

  float zmin = A.z, zmax = A.z;
#pragma unroll
  for (int off = 1; off < 64; off <<= 1) {
    zmin = fminf(zmin, __shfl_xor(zmin, off));
    zmax = fmaxf(zmax, __shfl_xor(zmax, off));
  }
  int klo = (int)((zmin - RAD) * ZSCALE) - 1; if (klo < 0) klo = 0;       // -1: fp slack
  int khi = (int)((zmax + RAD) * ZSCALE) + 1; if (khi > ZBINS - 1) khi = ZBINS - 1;
  const int jlo = b * NPTS + rsL[b * (ZBINS + 1) + klo];
  const int jhi = b * NPTS + rsL[b * (ZBINS + 1) + khi + 1];
  const int len = jhi - jlo;
  const int c0 = jlo + (len * (int)blockIdx.y) / YS;
  const int c1 = jlo + (len * ((int)blockIdx.y + 1)) / YS;

  float acc[D];
#pragma unroll
  for (int d = 0; d < D; ++d) acc[d] = 0.f;
  float nbc = 0.f, cnt = 0.f;

  auto process = [&](const float4 c, const int jj) {
    const float t = fmaf(A.z, c.z, fmaf(A.y, c.y, fmaf(A.x, c.x, mhsq)));
    if (t > c.w) {                        // d2 < R2, j is leaf by construction
      nbc += 1.0f;
      const float4* __restrict__ ej4 = (const float4*)(embL + (size_t)jj * D);
      float s0 = 0.f, s1 = 0.f, s2 = 0.f, s3 = 0.f;
#pragma unroll
      for (int k = 0; k < D / 4; ++k) {
        const float4 vj = ej4[k];
        const float4 vi = ei4[k];
        s0 = fmaf(vi.x, vj.x, s0);
        s1 = fmaf(vi.y, vj.y, s1);
        s2 = fmaf(vi.z, vj.z, s2);
        s3 = fmaf(vi.w, vj.w, s3);
      }
      const float s = ((s0 + s1) + (s2 + s3)) * inv_i * invL[jj];
      if (s > SIMT) {
        cnt += 1.0f;
#pragma unroll
        for (int k = 0; k < D / 4; ++k) {
          const float4 vj = ej4[k];
          acc[4 * k + 0] += vj.x;
          acc[4 * k + 1] += vj.y;
          acc[4 * k + 2] += vj.z;
          acc[4 * k + 3] += vj.w;
        }
      }
    }
  };

  int j = c0;
  for (; j + 3 < c1; j += 4) {
    const float4 q0 = pts4L[j + 0], q1 = pts4L[j + 1];
    const float4 q2 = pts4L[j + 2], q3 = pts4L[j + 3];
    process(q0, j + 0);
    process(q1, j + 1);
    process(q2, j + 2);
    process(q3, j + 3);
  }
  for (; j < c1; ++j) process(pts4L[j], j);

  float* __restrict__ q = part + (size_t)blockIdx.y * AFIELDS * BN + sg;
  q[0 * BN] = nbc;
  q[1 * BN] = cnt;
  if (cnt != 0.f) {
#pragma unroll
    for (int d = 0; d < D; ++d) q[(2 + d) * BN] = acc[d];
  }
}

// ---------------------------------------------------------------------------
// reduce + MLP + select (operates in sorted order; scatters out via perm)
// ---------------------------------------------------------------------------
template <int YS>
__global__ __launch_bounds__(BLOCK) void reduce_kernel(
    const float* __restrict__ part, const float4* __restrict__ sortedA,
    const int* __restrict__ permA, const float* __restrict__ emb,
    const float* __restrict__ W1, const float* __restrict__ b1,
    const float* __restrict__ W2, const float* __restrict__ b2,
    const int* __restrict__ leafcnt, float* __restrict__ out) {
  const int sg = blockIdx.x * BLOCK + threadIdx.x;
  const int b = sg >> 13;

  float nbc = 0.f, cnt = 0.f;
  float acc[D];
#pragma unroll
  for (int d = 0; d < D; ++d) acc[d] = 0.f;
#pragma unroll
  for (int js = 0; js < YS; ++js) {
    const float* __restrict__ q = part + (size_t)js * AFIELDS * BN + sg;
    nbc += q[0 * BN];
    const float c = q[1 * BN];
    cnt += c;
    if (c != 0.f) {
#pragma unroll
      for (int d = 0; d < D; ++d) acc[d] += q[(2 + d) * BN];
    }
  }

  const int p = permA[sg];
  float e[D];
  {
    const float4* er = (const float4*)(emb + (size_t)p * D);
#pragma unroll
    for (int i = 0; i < D / 4; ++i) {
      float4 v = er[i];
      e[4 * i + 0] = v.x; e[4 * i + 1] = v.y;
      e[4 * i + 2] = v.z; e[4 * i + 3] = v.w;
    }
  }

  const float rinv = 1.0f / fmaxf(cnt, 1.0f);
  float mean[D];
#pragma unroll
  for (int d = 0; d < D; ++d) mean[d] = acc[d] * rinv;

  float h[D];
#pragma unroll
  for (int k = 0; k < D; ++k) h[k] = b1[k];
  for (int d = 0; d < D; ++d) {
    const float c = e[d];
    const float* __restrict__ w = W1 + (size_t)d * D;
#pragma unroll
    for (int k = 0; k < D; ++k) h[k] = fmaf(c, w[k], h[k]);
  }
  for (int d = 0; d < D; ++d) {
    const float c = mean[d];
    const float* __restrict__ w = W1 + (size_t)(D + d) * D;
#pragma unroll
    for (int k = 0; k < D; ++k) h[k] = fmaf(c, w[k], h[k]);
  }
#pragma unroll
  for (int k = 0; k < D; ++k) h[k] = fmaxf(h[k], 0.f);

  float o[D];
#pragma unroll
  for (int m = 0; m < D; ++m) o[m] = b2[m];
  for (int k = 0; k < D; ++k) {
    const float c = h[k];
    const float* __restrict__ w = W2 + (size_t)k * D;
#pragma unroll
    for (int m = 0; m < D; ++m) o[m] = fmaf(c, w[m], o[m]);
  }

  const bool lf = sortedA[sg].w > 0.f;
  const bool cond = lf && (nbc >= 2.0f) && (cnt >= 1.0f) && (leafcnt[b] >= 10);

  float4* outr = (float4*)(out + (size_t)p * D);
#pragma unroll
  for (int i = 0; i < D / 4; ++i) {
    float4 v;
    if (cond) { v.x = o[4*i+0]; v.y = o[4*i+1]; v.z = o[4*i+2]; v.w = o[4*i+3]; }
    else      { v.x = e[4*i+0]; v.y = e[4*i+1]; v.z = e[4*i+2]; v.w = e[4*i+3]; }
    outr[i] = v;
  }
}

// ---------------------------------------------------------------------------
extern "C" void kernel_launch(void* const* d_in, const int* in_sizes, int n_in,
                              void* d_out, int out_size, void* d_ws, size_t ws_size,
                              hipStream_t stream) {
  (void)in_sizes; (void)n_in; (void)out_size;
  const float* pts  = (const float*)d_in[0];
  const float* emb  = (const float*)d_in[1];
  const int*   leaf = (const int*)d_in[2];
  const float* W1   = (const float*)d_in[3];
  const float* b1   = (const float*)d_in[4];
  const float* W2   = (const float*)d_in[5];
  const float* b2   = (const float*)d_in[6];
  float* out = (float*)d_out;

  char* ws = (char*)d_ws;
  size_t off = 0;
  auto alloc = [&](size_t bytes) { void* r = ws + off; off = (off + bytes + 15) & ~(size_t)15; return r; };

  // fixed tail first so part can take the rest
  float4* sortedA = (float4*)alloc((size_t)BN * 16);
  int*    permA   = (int*)alloc((size_t)BN * 4);
  float4* pts4L   = (float4*)alloc((size_t)BN * 16);
  float*  invL    = (float*)alloc((size_t)BN * 4);
  float*  embL    = (float*)alloc((size_t)BN * D * 4);
  float*  invn    = (float*)alloc((size_t)BN * 4);
  int*    rsA     = (int*)alloc(2 * (ZBINS + 1) * 4);
  int*    rsL     = (int*)alloc(2 * (ZBINS + 1) * 4);
  int*    curA    = (int*)alloc(2 * ZBINS * 4);
  int*    curL    = (int*)alloc(2 * ZBINS * 4);
  int*    histA   = (int*)alloc(2 * ZBINS * 4);   // histA..leafcnt contiguous
  int*    histL   = (int*)alloc(2 * ZBINS * 4);   //   for a single memset
  int*    leafcnt = (int*)alloc(16);
  float*  part    = (float*)(ws + off);
  const size_t chunk = (size_t)AFIELDS * BN * 4;  // 2.23 MB per y-chunk

  hipMemsetAsync(histA, 0, 2 * (2 * ZBINS * 4 + 8) + 16, stream);
  hist_kernel<<<BN / BLOCK, BLOCK, 0, stream>>>(pts, emb, leaf, invn, histA,
                                                histL, leafcnt);
  scan_kernel<<<1, ZBINS, 0, stream>>>(histA, histL, rsA, rsL, curA, curL);
  scatter_kernel<<<BN / BLOCK, BLOCK, 0, stream>>>(pts, emb, leaf, invn, curA,
                                                   curL, sortedA, permA, pts4L,
                                                   invL, embL);
  if (off + 16 * chunk <= ws_size) {
    pair_kernel<16><<<dim3(BN / 64, 16), 64, 0, stream>>>(
        sortedA, permA, pts4L, invL, embL, emb, rsL, part);
    reduce_kernel<16><<<BN / BLOCK, BLOCK, 0, stream>>>(
        part, sortedA, permA, emb, W1, b1, W2, b2, leafcnt, out);
  } else if (off + 8 * chunk <= ws_size) {
    pair_kernel<8><<<dim3(BN / 64, 8), 64, 0, stream>>>(
        sortedA, permA, pts4L, invL, embL, emb, rsL, part);
    reduce_kernel<8><<<BN / BLOCK, BLOCK, 0, stream>>>(
        part, sortedA, permA, emb, W1, b1, W2, b2, leafcnt, out);
  } else {
    pair_kernel<4><<<dim3(BN / 64, 4), 64, 0, stream>>>(
        sortedA, permA, pts4L, invL, embL, emb, rsL, part);
    reduce_kernel<4><<<BN / BLOCK, BLOCK, 0, stream>>>(
        part, sortedA, permA, emb, W1, b1, W2, b2, leafcnt, out);
  }
}

// Round 6
// 166.592 us; speedup vs baseline: 3.2617x; 1.0063x over previous
//
#include <hip/hip_runtime.h>

#define NPTS 8192
#define BN   16384          // B * N
#define D    32
#define R2   0.0009f        // float32(0.03**2)
#define SIMT 0.7f
#define RAD  0.03f
#define BLOCK 256
#define ZBINS 512
#define ZSCALE 1280.0f      // ZBINS / 0.4 (points lie in [0, 0.4))
#define AFIELDS 34          // nbc, cnt, acc[32] — SoA, field stride BN
#define YG 8                // global window slices (each block's 4 waves sub-split)

// ---------------------------------------------------------------------------
// hist: z-histogram (all points + leaf-only), inv-norms, per-batch leaf count
// ---------------------------------------------------------------------------
__global__ __launch_bounds__(BLOCK) void hist_kernel(
    const float* __restrict__ pts, const float* __restrict__ emb,
    const int* __restrict__ leaf, float* __restrict__ invn,
    int* __restrict__ histA, int* __restrict__ histL, int* __restrict__ leafcnt) {
  const int p = blockIdx.x * BLOCK + threadIdx.x;
  const float z = pts[3 * p + 2];
  int bin = (int)(z * ZSCALE); if (bin > ZBINS - 1) bin = ZBINS - 1;
  const int b = p >> 13;
  const int lf = leaf[p] > 0;
  atomicAdd(&histA[b * ZBINS + bin], 1);
  if (lf) atomicAdd(&histL[b * ZBINS + bin], 1);

  const float4* er = (const float4*)(emb + (size_t)p * D);
  float ss = 0.f;
#pragma unroll
  for (int i = 0; i < D / 4; ++i) {
    float4 v = er[i];
    ss += v.x * v.x + v.y * v.y + v.z * v.z + v.w * v.w;
  }
  invn[p] = 1.0f / fmaxf(sqrtf(ss), 1e-8f);

  const unsigned long long m = __ballot(lf);
  if ((threadIdx.x & 63) == 0) atomicAdd(&leafcnt[b], (int)__popcll(m));
}

// ---------------------------------------------------------------------------
// scan: exclusive prefix sums for both hists, both batches; init cursors
// ---------------------------------------------------------------------------
__global__ __launch_bounds__(ZBINS) void scan_kernel(
    const int* __restrict__ histA, const int* __restrict__ histL,
    int* __restrict__ rsA, int* __restrict__ rsL,
    int* __restrict__ curA, int* __restrict__ curL) {
  __shared__ int buf[ZBINS];
  const int t = threadIdx.x;
  for (int sel = 0; sel < 4; ++sel) {
    const int b = sel & 1;
    const int* __restrict__ h = (sel < 2) ? histA : histL;
    int* __restrict__ rs = (sel < 2) ? rsA : rsL;
    int* __restrict__ cu = (sel < 2) ? curA : curL;
    const int mine = h[b * ZBINS + t];
    int val = mine;
    buf[t] = mine;
    __syncthreads();
    for (int off = 1; off < ZBINS; off <<= 1) {
      const int other = (t >= off) ? buf[t - off] : 0;
      __syncthreads();
      val += other;
      buf[t] = val;
      __syncthreads();
    }
    const int excl = val - mine;
    rs[b * (ZBINS + 1) + t] = excl;
    cu[b * ZBINS + t] = excl;
    if (t == ZBINS - 1) rs[b * (ZBINS + 1) + ZBINS] = val;
    __syncthreads();
  }
}

// ---------------------------------------------------------------------------
// scatter: counting-sort by z-bin. All points -> sortedA (+perm); leaf points
// -> compacted j-side arrays (pts4L with folded 0.5*(sq-R2), invL, embL).
// ---------------------------------------------------------------------------
__global__ __launch_bounds__(BLOCK) void scatter_kernel(
    const float* __restrict__ pts, const float* __restrict__ emb,
    const int* __restrict__ leaf, const float* __restrict__ invn,
    int* __restrict__ curA, int* __restrict__ curL,
    float4* __restrict__ sortedA, int* __restrict__ permA,
    float4* __restrict__ pts4L, float* __restrict__ invL,
    float* __restrict__ embL) {
  const int p = blockIdx.x * BLOCK + threadIdx.x;
  const float x = pts[3 * p + 0];
  const float y = pts[3 * p + 1];
  const float z = pts[3 * p + 2];
  const float sq = x * x + y * y + z * z;
  const int lf = leaf[p] > 0;
  const float inv = invn[p];
  int bin = (int)(z * ZSCALE); if (bin > ZBINS - 1) bin = ZBINS - 1;
  const int b = p >> 13;

  const int dst = b * NPTS + atomicAdd(&curA[b * ZBINS + bin], 1);
  sortedA[dst] = make_float4(x, y, z, lf ? inv : -inv);  // leaf in sign bit
  permA[dst] = p;

  if (lf) {
    const int dl = b * NPTS + atomicAdd(&curL[b * ZBINS + bin], 1);
    pts4L[dl] = make_float4(x, y, z, 0.5f * (sq - R2));
    invL[dl] = inv;
    const float4* __restrict__ s4 = (const float4*)(emb + (size_t)p * D);
    float4* __restrict__ d4 = (float4*)(embL + (size_t)dl * D);
#pragma unroll
    for (int k = 0; k < D / 4; ++k) d4[k] = s4[k];
  }
}

// ---------------------------------------------------------------------------
// pair: block = 4 waves on the SAME 64 sorted i's; wave w scans window-slice
// (blockIdx.y*4 + w) of 32. Bounds forced uniform via readfirstlane so the
// j-side loads scalarize (R5 lost this: SGPR 112->32). Waves combine in LDS;
// wave 0 writes one 34-field partial per i per y-slice (all fields, no holes).
// ---------------------------------------------------------------------------
__global__ __launch_bounds__(BLOCK) void pair_kernel(
    const float4* __restrict__ sortedA, const int* __restrict__ permA,
    const float4* __restrict__ pts4L, const float* __restrict__ invL,
    const float* __restrict__ embL, const float* __restrict__ emb,
    const int* __restrict__ rsL, float* __restrict__ part) {
  const int ig   = blockIdx.x;            // i-group of 64
  const int b    = ig >> 7;               // 128 i-groups per batch
  const int lane = threadIdx.x & 63;
  const int wv   = threadIdx.x >> 6;      // wave 0..3
  const int sg   = ig * 64 + lane;

  __shared__ float red[AFIELDS][64];
  for (int t = threadIdx.x; t < AFIELDS * 64; t += BLOCK)
    (&red[0][0])[t] = 0.f;
  __syncthreads();

  const float4 A = sortedA[sg];
  const float inv_i = fabsf(A.w);
  const float mhsq = -0.5f * (A.x * A.x + A.y * A.y + A.z * A.z);
  const int p = permA[sg];

  // hoist e_i into registers (one gather per wave, not per hit)
  float4 ei[D / 4];
  {
    const float4* __restrict__ e4 = (const float4*)(emb + (size_t)p * D);
#pragma unroll
    for (int k = 0; k < D / 4; ++k) ei[k] = e4[k];
  }

  float zmin = A.z, zmax = A.z;
#pragma unroll
  for (int off = 1; off < 64; off <<= 1) {
    zmin = fminf(zmin, __shfl_xor(zmin, off));
    zmax = fmaxf(zmax, __shfl_xor(zmax, off));
  }
  int klo = (int)((zmin - RAD) * ZSCALE) - 1; if (klo < 0) klo = 0;  // fp slack
  int khi = (int)((zmax + RAD) * ZSCALE) + 1; if (khi > ZBINS - 1) khi = ZBINS - 1;
  klo = __builtin_amdgcn_readfirstlane(klo);
  khi = __builtin_amdgcn_readfirstlane(khi);
  const int jlo = b * NPTS + rsL[b * (ZBINS + 1) + klo];
  const int jhi = b * NPTS + rsL[b * (ZBINS + 1) + khi + 1];
  const int len = jhi - jlo;
  const int sl  = blockIdx.y * 4 + wv;    // 0..31
  int c0 = jlo + (len * sl) / 32;
  int c1 = jlo + (len * (sl + 1)) / 32;
  c0 = __builtin_amdgcn_readfirstlane(c0);
  c1 = __builtin_amdgcn_readfirstlane(c1);

  float acc[D];
#pragma unroll
  for (int d = 0; d < D; ++d) acc[d] = 0.f;
  float nbc = 0.f, cnt = 0.f;

  auto process = [&](const float4 c, const int jj) {
    const float t = fmaf(A.z, c.z, fmaf(A.y, c.y, fmaf(A.x, c.x, mhsq)));
    if (t > c.w) {                        // d2 < R2; j is leaf by construction
      nbc += 1.0f;
      const float4* __restrict__ ej4 = (const float4*)(embL + (size_t)jj * D);
      float s0 = 0.f, s1 = 0.f, s2 = 0.f, s3 = 0.f;
#pragma unroll
      for (int k = 0; k < D / 4; ++k) {
        const float4 vj = ej4[k];         // uniform jj -> scalar loads
        s0 = fmaf(ei[k].x, vj.x, s0);
        s1 = fmaf(ei[k].y, vj.y, s1);
        s2 = fmaf(ei[k].z, vj.z, s2);
        s3 = fmaf(ei[k].w, vj.w, s3);
      }
      const float s = ((s0 + s1) + (s2 + s3)) * inv_i * invL[jj];
      if (s > SIMT) {
        cnt += 1.0f;
#pragma unroll
        for (int k = 0; k < D / 4; ++k) {
          const float4 vj = ej4[k];
          acc[4 * k + 0] += vj.x;
          acc[4 * k + 1] += vj.y;
          acc[4 * k + 2] += vj.z;
          acc[4 * k + 3] += vj.w;
        }
      }
    }
  };

  const int nfull = (c1 - c0) & ~3;
  if (nfull > 0) {
    float4 cur[4], nxt[4];
#pragma unroll
    for (int u = 0; u < 4; ++u) cur[u] = pts4L[c0 + u];
    for (int j = c0; j < c0 + nfull; j += 4) {
      const int jn = (j + 4 < c0 + nfull) ? (j + 4) : c0;  // wrap: in-bounds
#pragma unroll
      for (int u = 0; u < 4; ++u) nxt[u] = pts4L[jn + u];
#pragma unroll
      for (int u = 0; u < 4; ++u) process(cur[u], j + u);
#pragma unroll
      for (int u = 0; u < 4; ++u) cur[u] = nxt[u];
    }
  }
  for (int j = c0 + nfull; j < c1; ++j) process(pts4L[j], j);

  // combine the block's 4 waves in LDS (sparse atomics; ds_add_f32)
  if (nbc != 0.f) atomicAdd(&red[0][lane], nbc);
  if (cnt != 0.f) {
    atomicAdd(&red[1][lane], cnt);
#pragma unroll
    for (int d = 0; d < D; ++d) atomicAdd(&red[2 + d][lane], acc[d]);
  }
  __syncthreads();

  if (threadIdx.x < 64) {
    float* __restrict__ q = part + (size_t)blockIdx.y * AFIELDS * BN
                          + (size_t)ig * 64 + threadIdx.x;
#pragma unroll
    for (int f = 0; f < AFIELDS; ++f) q[(size_t)f * BN] = red[f][threadIdx.x];
  }
}

// ---------------------------------------------------------------------------
// reduce + MLP + select (sorted order; scatters out via perm)
// ---------------------------------------------------------------------------
__global__ __launch_bounds__(BLOCK) void reduce_kernel(
    const float* __restrict__ part, const float4* __restrict__ sortedA,
    const int* __restrict__ permA, const float* __restrict__ emb,
    const float* __restrict__ W1, const float* __restrict__ b1,
    const float* __restrict__ W2, const float* __restrict__ b2,
    const int* __restrict__ leafcnt, float* __restrict__ out) {
  const int sg = blockIdx.x * BLOCK + threadIdx.x;
  const int b = sg >> 13;

  float nbc = 0.f, cnt = 0.f;
  float acc[D];
#pragma unroll
  for (int d = 0; d < D; ++d) acc[d] = 0.f;
#pragma unroll
  for (int js = 0; js < YG; ++js) {
    const float* __restrict__ q = part + (size_t)js * AFIELDS * BN + sg;
    nbc += q[0 * BN];
    cnt += q[1 * BN];
#pragma unroll
    for (int d = 0; d < D; ++d) acc[d] += q[(2 + d) * BN];
  }

  const int p = permA[sg];
  float e[D];
  {
    const float4* er = (const float4*)(emb + (size_t)p * D);
#pragma unroll
    for (int i = 0; i < D / 4; ++i) {
      float4 v = er[i];
      e[4 * i + 0] = v.x; e[4 * i + 1] = v.y;
      e[4 * i + 2] = v.z; e[4 * i + 3] = v.w;
    }
  }

  const float rinv = 1.0f / fmaxf(cnt, 1.0f);
  float mean[D];
#pragma unroll
  for (int d = 0; d < D; ++d) mean[d] = acc[d] * rinv;

  float h[D];
#pragma unroll
  for (int k = 0; k < D; ++k) h[k] = b1[k];
  for (int d = 0; d < D; ++d) {
    const float c = e[d];
    const float* __restrict__ w = W1 + (size_t)d * D;
#pragma unroll
    for (int k = 0; k < D; ++k) h[k] = fmaf(c, w[k], h[k]);
  }
  for (int d = 0; d < D; ++d) {
    const float c = mean[d];
    const float* __restrict__ w = W1 + (size_t)(D + d) * D;
#pragma unroll
    for (int k = 0; k < D; ++k) h[k] = fmaf(c, w[k], h[k]);
  }
#pragma unroll
  for (int k = 0; k < D; ++k) h[k] = fmaxf(h[k], 0.f);

  float o[D];
#pragma unroll
  for (int m = 0; m < D; ++m) o[m] = b2[m];
  for (int k = 0; k < D; ++k) {
    const float c = h[k];
    const float* __restrict__ w = W2 + (size_t)k * D;
#pragma unroll
    for (int m = 0; m < D; ++m) o[m] = fmaf(c, w[m], o[m]);
  }

  const bool lf = sortedA[sg].w > 0.f;
  const bool cond = lf && (nbc >= 2.0f) && (cnt >= 1.0f) && (leafcnt[b] >= 10);

  float4* outr = (float4*)(out + (size_t)p * D);
#pragma unroll
  for (int i = 0; i < D / 4; ++i) {
    float4 v;
    if (cond) { v.x = o[4*i+0]; v.y = o[4*i+1]; v.z = o[4*i+2]; v.w = o[4*i+3]; }
    else      { v.x = e[4*i+0]; v.y = e[4*i+1]; v.z = e[4*i+2]; v.w = e[4*i+3]; }
    outr[i] = v;
  }
}

// ---------------------------------------------------------------------------
extern "C" void kernel_launch(void* const* d_in, const int* in_sizes, int n_in,
                              void* d_out, int out_size, void* d_ws, size_t ws_size,
                              hipStream_t stream) {
  (void)in_sizes; (void)n_in; (void)out_size; (void)ws_size;
  const float* pts  = (const float*)d_in[0];
  const float* emb  = (const float*)d_in[1];
  const int*   leaf = (const int*)d_in[2];
  const float* W1   = (const float*)d_in[3];
  const float* b1   = (const float*)d_in[4];
  const float* W2   = (const float*)d_in[5];
  const float* b2   = (const float*)d_in[6];
  float* out = (float*)d_out;

  char* ws = (char*)d_ws;
  size_t off = 0;
  auto alloc = [&](size_t bytes) { void* r = ws + off; off = (off + bytes + 15) & ~(size_t)15; return r; };

  float4* sortedA = (float4*)alloc((size_t)BN * 16);
  int*    permA   = (int*)alloc((size_t)BN * 4);
  float4* pts4L   = (float4*)alloc((size_t)BN * 16);
  float*  invL    = (float*)alloc((size_t)BN * 4);
  float*  embL    = (float*)alloc((size_t)BN * D * 4);
  float*  invn    = (float*)alloc((size_t)BN * 4);
  int*    rsA     = (int*)alloc(2 * (ZBINS + 1) * 4);
  int*    rsL     = (int*)alloc(2 * (ZBINS + 1) * 4);
  int*    curA    = (int*)alloc(2 * ZBINS * 4);
  int*    curL    = (int*)alloc(2 * ZBINS * 4);
  int*    histA   = (int*)alloc(2 * ZBINS * 4);   // histA..leafcnt contiguous
  int*    histL   = (int*)alloc(2 * ZBINS * 4);   //   for a single memset
  int*    leafcnt = (int*)alloc(16);
  float*  part    = (float*)(ws + off);           // YG * 2.23 MB = 17.8 MB

  hipMemsetAsync(histA, 0, 2 * (2 * ZBINS * 4) + 16, stream);
  hist_kernel<<<BN / BLOCK, BLOCK, 0, stream>>>(pts, emb, leaf, invn, histA,
                                                histL, leafcnt);
  scan_kernel<<<1, ZBINS, 0, stream>>>(histA, histL, rsA, rsL, curA, curL);
  scatter_kernel<<<BN / BLOCK, BLOCK, 0, stream>>>(pts, emb, leaf, invn, curA,
                                                   curL, sortedA, permA, pts4L,
                                                   invL, embL);
  pair_kernel<<<dim3(BN / 64, YG), BLOCK, 0, stream>>>(
      sortedA, permA, pts4L, invL, embL, emb, rsL, part);
  reduce_kernel<<<BN / BLOCK, BLOCK, 0, stream>>>(
      part, sortedA, permA, emb, W1, b1, W2, b2, leafcnt, out);
}

// Round 7
// 140.886 us; speedup vs baseline: 3.8569x; 1.1825x over previous
//
#include <hip/hip_runtime.h>

#define NPTS 8192
#define BN   16384          // B * N
#define D    32
#define R2   0.0009f        // float32(0.03**2)
#define SIMT 0.7f
#define RAD  0.03f
#define BLOCK 256
#define ZBINS 512
#define ZSCALE 1280.0f      // ZBINS / 0.4 (points lie in [0, 0.4))
#define AFIELDS 34          // nbc, cnt, acc[32] — SoA, field stride BN
#define YG 8                // global window slices (each block's 4 waves sub-split)

// ---------------------------------------------------------------------------
// hist: z-histogram (all points + leaf-only), inv-norms, per-batch leaf count
// ---------------------------------------------------------------------------
__global__ __launch_bounds__(BLOCK) void hist_kernel(
    const float* __restrict__ pts, const float* __restrict__ emb,
    const int* __restrict__ leaf, float* __restrict__ invn,
    int* __restrict__ histA, int* __restrict__ histL, int* __restrict__ leafcnt) {
  const int p = blockIdx.x * BLOCK + threadIdx.x;
  const float z = pts[3 * p + 2];
  int bin = (int)(z * ZSCALE); if (bin > ZBINS - 1) bin = ZBINS - 1;
  const int b = p >> 13;
  const int lf = leaf[p] > 0;
  atomicAdd(&histA[b * ZBINS + bin], 1);
  if (lf) atomicAdd(&histL[b * ZBINS + bin], 1);

  const float4* er = (const float4*)(emb + (size_t)p * D);
  float ss = 0.f;
#pragma unroll
  for (int i = 0; i < D / 4; ++i) {
    float4 v = er[i];
    ss += v.x * v.x + v.y * v.y + v.z * v.z + v.w * v.w;
  }
  invn[p] = 1.0f / fmaxf(sqrtf(ss), 1e-8f);

  const unsigned long long m = __ballot(lf);
  if ((threadIdx.x & 63) == 0) atomicAdd(&leafcnt[b], (int)__popcll(m));
}

// ---------------------------------------------------------------------------
// scan: exclusive prefix sums for both hists, both batches; init cursors
// ---------------------------------------------------------------------------
__global__ __launch_bounds__(ZBINS) void scan_kernel(
    const int* __restrict__ histA, const int* __restrict__ histL,
    int* __restrict__ rsA, int* __restrict__ rsL,
    int* __restrict__ curA, int* __restrict__ curL) {
  __shared__ int buf[ZBINS];
  const int t = threadIdx.x;
  for (int sel = 0; sel < 4; ++sel) {
    const int b = sel & 1;
    const int* __restrict__ h = (sel < 2) ? histA : histL;
    int* __restrict__ rs = (sel < 2) ? rsA : rsL;
    int* __restrict__ cu = (sel < 2) ? curA : curL;
    const int mine = h[b * ZBINS + t];
    int val = mine;
    buf[t] = mine;
    __syncthreads();
    for (int off = 1; off < ZBINS; off <<= 1) {
      const int other = (t >= off) ? buf[t - off] : 0;
      __syncthreads();
      val += other;
      buf[t] = val;
      __syncthreads();
    }
    const int excl = val - mine;
    rs[b * (ZBINS + 1) + t] = excl;
    cu[b * ZBINS + t] = excl;
    if (t == ZBINS - 1) rs[b * (ZBINS + 1) + ZBINS] = val;
    __syncthreads();
  }
}

// ---------------------------------------------------------------------------
// scatter: counting-sort by z-bin. All points -> sortedA (+perm); leaf points
// -> compacted j-side arrays (pts4L with folded 0.5*(sq-R2), invL, embL).
// ---------------------------------------------------------------------------
__global__ __launch_bounds__(BLOCK) void scatter_kernel(
    const float* __restrict__ pts, const float* __restrict__ emb,
    const int* __restrict__ leaf, const float* __restrict__ invn,
    int* __restrict__ curA, int* __restrict__ curL,
    float4* __restrict__ sortedA, int* __restrict__ permA,
    float4* __restrict__ pts4L, float* __restrict__ invL,
    float* __restrict__ embL) {
  const int p = blockIdx.x * BLOCK + threadIdx.x;
  const float x = pts[3 * p + 0];
  const float y = pts[3 * p + 1];
  const float z = pts[3 * p + 2];
  const float sq = x * x + y * y + z * z;
  const int lf = leaf[p] > 0;
  const float inv = invn[p];
  int bin = (int)(z * ZSCALE); if (bin > ZBINS - 1) bin = ZBINS - 1;
  const int b = p >> 13;

  const int dst = b * NPTS + atomicAdd(&curA[b * ZBINS + bin], 1);
  sortedA[dst] = make_float4(x, y, z, lf ? inv : -inv);  // leaf in sign bit
  permA[dst] = p;

  if (lf) {
    const int dl = b * NPTS + atomicAdd(&curL[b * ZBINS + bin], 1);
    pts4L[dl] = make_float4(x, y, z, 0.5f * (sq - R2));
    invL[dl] = inv;
    const float4* __restrict__ s4 = (const float4*)(emb + (size_t)p * D);
    float4* __restrict__ d4 = (float4*)(embL + (size_t)dl * D);
#pragma unroll
    for (int k = 0; k < D / 4; ++k) d4[k] = s4[k];
  }
}

// ---------------------------------------------------------------------------
// pair: block = 4 waves on the SAME 64 sorted i's; wave w scans window-slice
// (blockIdx.y*4 + w) of 32. Bounds forced uniform via readfirstlane so the
// j-side loads scalarize. Waves combine in LDS; wave 0 writes all 34 fields
// (zeros included) so reduce may skip acc when slice-cnt==0 (acc!=0 => cnt>=1).
// ---------------------------------------------------------------------------
__global__ __launch_bounds__(BLOCK) void pair_kernel(
    const float4* __restrict__ sortedA, const int* __restrict__ permA,
    const float4* __restrict__ pts4L, const float* __restrict__ invL,
    const float* __restrict__ embL, const float* __restrict__ emb,
    const int* __restrict__ rsL, float* __restrict__ part) {
  const int ig   = blockIdx.x;            // i-group of 64
  const int b    = ig >> 7;               // 128 i-groups per batch
  const int lane = threadIdx.x & 63;
  const int wv   = threadIdx.x >> 6;      // wave 0..3
  const int sg   = ig * 64 + lane;

  __shared__ float red[AFIELDS][64];
  for (int t = threadIdx.x; t < AFIELDS * 64; t += BLOCK)
    (&red[0][0])[t] = 0.f;
  __syncthreads();

  const float4 A = sortedA[sg];
  const float inv_i = fabsf(A.w);
  const float mhsq = -0.5f * (A.x * A.x + A.y * A.y + A.z * A.z);
  const int p = permA[sg];

  // hoist e_i into registers (one gather per wave, not per hit)
  float4 ei[D / 4];
  {
    const float4* __restrict__ e4 = (const float4*)(emb + (size_t)p * D);
#pragma unroll
    for (int k = 0; k < D / 4; ++k) ei[k] = e4[k];
  }

  float zmin = A.z, zmax = A.z;
#pragma unroll
  for (int off = 1; off < 64; off <<= 1) {
    zmin = fminf(zmin, __shfl_xor(zmin, off));
    zmax = fmaxf(zmax, __shfl_xor(zmax, off));
  }
  int klo = (int)((zmin - RAD) * ZSCALE) - 1; if (klo < 0) klo = 0;  // fp slack
  int khi = (int)((zmax + RAD) * ZSCALE) + 1; if (khi > ZBINS - 1) khi = ZBINS - 1;
  klo = __builtin_amdgcn_readfirstlane(klo);
  khi = __builtin_amdgcn_readfirstlane(khi);
  const int jlo = b * NPTS + rsL[b * (ZBINS + 1) + klo];
  const int jhi = b * NPTS + rsL[b * (ZBINS + 1) + khi + 1];
  const int len = jhi - jlo;
  const int sl  = blockIdx.y * 4 + wv;    // 0..31
  int c0 = jlo + (len * sl) / 32;
  int c1 = jlo + (len * (sl + 1)) / 32;
  c0 = __builtin_amdgcn_readfirstlane(c0);
  c1 = __builtin_amdgcn_readfirstlane(c1);

  float acc[D];
#pragma unroll
  for (int d = 0; d < D; ++d) acc[d] = 0.f;
  float nbc = 0.f, cnt = 0.f;

  auto process = [&](const float4 c, const int jj) {
    const float t = fmaf(A.z, c.z, fmaf(A.y, c.y, fmaf(A.x, c.x, mhsq)));
    if (t > c.w) {                        // d2 < R2; j is leaf by construction
      nbc += 1.0f;
      const float4* __restrict__ ej4 = (const float4*)(embL + (size_t)jj * D);
      float s0 = 0.f, s1 = 0.f, s2 = 0.f, s3 = 0.f;
#pragma unroll
      for (int k = 0; k < D / 4; ++k) {
        const float4 vj = ej4[k];         // uniform jj -> scalar loads
        s0 = fmaf(ei[k].x, vj.x, s0);
        s1 = fmaf(ei[k].y, vj.y, s1);
        s2 = fmaf(ei[k].z, vj.z, s2);
        s3 = fmaf(ei[k].w, vj.w, s3);
      }
      const float s = ((s0 + s1) + (s2 + s3)) * inv_i * invL[jj];
      if (s > SIMT) {
        cnt += 1.0f;
#pragma unroll
        for (int k = 0; k < D / 4; ++k) {
          const float4 vj = ej4[k];
          acc[4 * k + 0] += vj.x;
          acc[4 * k + 1] += vj.y;
          acc[4 * k + 2] += vj.z;
          acc[4 * k + 3] += vj.w;
        }
      }
    }
  };

  const int nfull = (c1 - c0) & ~3;
  if (nfull > 0) {
    float4 cur[4], nxt[4];
#pragma unroll
    for (int u = 0; u < 4; ++u) cur[u] = pts4L[c0 + u];
    for (int j = c0; j < c0 + nfull; j += 4) {
      const int jn = (j + 4 < c0 + nfull) ? (j + 4) : c0;  // wrap: in-bounds
#pragma unroll
      for (int u = 0; u < 4; ++u) nxt[u] = pts4L[jn + u];
#pragma unroll
      for (int u = 0; u < 4; ++u) process(cur[u], j + u);
#pragma unroll
      for (int u = 0; u < 4; ++u) cur[u] = nxt[u];
    }
  }
  for (int j = c0 + nfull; j < c1; ++j) process(pts4L[j], j);

  // combine the block's 4 waves in LDS (sparse atomics; ds_add_f32)
  if (nbc != 0.f) atomicAdd(&red[0][lane], nbc);
  if (cnt != 0.f) {
    atomicAdd(&red[1][lane], cnt);
#pragma unroll
    for (int d = 0; d < D; ++d) atomicAdd(&red[2 + d][lane], acc[d]);
  }
  __syncthreads();

  if (threadIdx.x < 64) {
    float* __restrict__ q = part + (size_t)blockIdx.y * AFIELDS * BN
                          + (size_t)ig * 64 + threadIdx.x;
#pragma unroll
    for (int f = 0; f < AFIELDS; ++f) q[(size_t)f * BN] = red[f][threadIdx.x];
  }
}

// ---------------------------------------------------------------------------
// reduce + MLP + select (sorted order; scatters out via perm).
// acc fields of a slice are read ONLY when that slice's cnt != 0 — exact,
// since acc != 0 implies cnt >= 1. This was R5's structure; R6's unconditional
// reads made reduce request-parallelism-bound (272 strided loads x 256 waves).
// ---------------------------------------------------------------------------
__global__ __launch_bounds__(BLOCK) void reduce_kernel(
    const float* __restrict__ part, const float4* __restrict__ sortedA,
    const int* __restrict__ permA, const float* __restrict__ emb,
    const float* __restrict__ W1, const float* __restrict__ b1,
    const float* __restrict__ W2, const float* __restrict__ b2,
    const int* __restrict__ leafcnt, float* __restrict__ out) {
  const int sg = blockIdx.x * BLOCK + threadIdx.x;
  const int b = sg >> 13;

  float nbc = 0.f, cnt = 0.f;
  float acc[D];
#pragma unroll
  for (int d = 0; d < D; ++d) acc[d] = 0.f;
#pragma unroll
  for (int js = 0; js < YG; ++js) {
    const float* __restrict__ q = part + (size_t)js * AFIELDS * BN + sg;
    nbc += q[0 * BN];
    const float c = q[1 * BN];
    cnt += c;
    if (c != 0.f) {          // sparse: typically <=1 of 8 slices per point
#pragma unroll
      for (int d = 0; d < D; ++d) acc[d] += q[(2 + d) * BN];
    }
  }

  const int p = permA[sg];
  float e[D];
  {
    const float4* er = (const float4*)(emb + (size_t)p * D);
#pragma unroll
    for (int i = 0; i < D / 4; ++i) {
      float4 v = er[i];
      e[4 * i + 0] = v.x; e[4 * i + 1] = v.y;
      e[4 * i + 2] = v.z; e[4 * i + 3] = v.w;
    }
  }

  const float rinv = 1.0f / fmaxf(cnt, 1.0f);
  float mean[D];
#pragma unroll
  for (int d = 0; d < D; ++d) mean[d] = acc[d] * rinv;

  float h[D];
#pragma unroll
  for (int k = 0; k < D; ++k) h[k] = b1[k];
  for (int d = 0; d < D; ++d) {
    const float c = e[d];
    const float* __restrict__ w = W1 + (size_t)d * D;
#pragma unroll
    for (int k = 0; k < D; ++k) h[k] = fmaf(c, w[k], h[k]);
  }
  for (int d = 0; d < D; ++d) {
    const float c = mean[d];
    const float* __restrict__ w = W1 + (size_t)(D + d) * D;
#pragma unroll
    for (int k = 0; k < D; ++k) h[k] = fmaf(c, w[k], h[k]);
  }
#pragma unroll
  for (int k = 0; k < D; ++k) h[k] = fmaxf(h[k], 0.f);

  float o[D];
#pragma unroll
  for (int m = 0; m < D; ++m) o[m] = b2[m];
  for (int k = 0; k < D; ++k) {
    const float c = h[k];
    const float* __restrict__ w = W2 + (size_t)k * D;
#pragma unroll
    for (int m = 0; m < D; ++m) o[m] = fmaf(c, w[m], o[m]);
  }

  const bool lf = sortedA[sg].w > 0.f;
  const bool cond = lf && (nbc >= 2.0f) && (cnt >= 1.0f) && (leafcnt[b] >= 10);

  float4* outr = (float4*)(out + (size_t)p * D);
#pragma unroll
  for (int i = 0; i < D / 4; ++i) {
    float4 v;
    if (cond) { v.x = o[4*i+0]; v.y = o[4*i+1]; v.z = o[4*i+2]; v.w = o[4*i+3]; }
    else      { v.x = e[4*i+0]; v.y = e[4*i+1]; v.z = e[4*i+2]; v.w = e[4*i+3]; }
    outr[i] = v;
  }
}

// ---------------------------------------------------------------------------
extern "C" void kernel_launch(void* const* d_in, const int* in_sizes, int n_in,
                              void* d_out, int out_size, void* d_ws, size_t ws_size,
                              hipStream_t stream) {
  (void)in_sizes; (void)n_in; (void)out_size; (void)ws_size;
  const float* pts  = (const float*)d_in[0];
  const float* emb  = (const float*)d_in[1];
  const int*   leaf = (const int*)d_in[2];
  const float* W1   = (const float*)d_in[3];
  const float* b1   = (const float*)d_in[4];
  const float* W2   = (const float*)d_in[5];
  const float* b2   = (const float*)d_in[6];
  float* out = (float*)d_out;

  char* ws = (char*)d_ws;
  size_t off = 0;
  auto alloc = [&](size_t bytes) { void* r = ws + off; off = (off + bytes + 15) & ~(size_t)15; return r; };

  float4* sortedA = (float4*)alloc((size_t)BN * 16);
  int*    permA   = (int*)alloc((size_t)BN * 4);
  float4* pts4L   = (float4*)alloc((size_t)BN * 16);
  float*  invL    = (float*)alloc((size_t)BN * 4);
  float*  embL    = (float*)alloc((size_t)BN * D * 4);
  float*  invn    = (float*)alloc((size_t)BN * 4);
  int*    rsA     = (int*)alloc(2 * (ZBINS + 1) * 4);
  int*    rsL     = (int*)alloc(2 * (ZBINS + 1) * 4);
  int*    curA    = (int*)alloc(2 * ZBINS * 4);
  int*    curL    = (int*)alloc(2 * ZBINS * 4);
  int*    histA   = (int*)alloc(2 * ZBINS * 4);   // histA..leafcnt contiguous
  int*    histL   = (int*)alloc(2 * ZBINS * 4);   //   for a single memset
  int*    leafcnt = (int*)alloc(16);
  float*  part    = (float*)(ws + off);           // YG * 2.23 MB = 17.8 MB

  hipMemsetAsync(histA, 0, 2 * (2 * ZBINS * 4) + 16, stream);
  hist_kernel<<<BN / BLOCK, BLOCK, 0, stream>>>(pts, emb, leaf, invn, histA,
                                                histL, leafcnt);
  scan_kernel<<<1, ZBINS, 0, stream>>>(histA, histL, rsA, rsL, curA, curL);
  scatter_kernel<<<BN / BLOCK, BLOCK, 0, stream>>>(pts, emb, leaf, invn, curA,
                                                   curL, sortedA, permA, pts4L,
                                                   invL, embL);
  pair_kernel<<<dim3(BN / 64, YG), BLOCK, 0, stream>>>(
      sortedA, permA, pts4L, invL, embL, emb, rsL, part);
  reduce_kernel<<<BN / BLOCK, BLOCK, 0, stream>>>(
      part, sortedA, permA, emb, W1, b1, W2, b2, leafcnt, out);
}